// Round 7
// baseline (13.495 us; speedup 1.0000x reference)
//
#include <hip/hip_runtime.h>
#include <hip/hip_bf16.h>

// out[b] = dot(user_factors[user_indices[b]], s)
// s[f]   = sum_c item_factors[item_indices[c], f],  F = 64
//
// 2 graph nodes, no memset, no atomics:
//   node 1: mf_item_sum (256 blocks, whole chip) -> s_part[256][64] stores
//   node 2: mf_user_dot (512 blocks): issue user gathers FIRST, then reduce
//           the 256 s-copies (L2-hot) while gathers are in flight, then dot.
// Lane decomposition: rg = lane>>4 (row 0..3), fs = lane&15 (float4 slice)
// -> one dwordx4 wave-instruction fetches 4 full 256 B rows, coalesced.

#define FDIM 64
#define NB1 256           // item_sum blocks == number of s copies
#define NB2 512           // user_dot blocks
#define NTHREADS 256
#define WPB 4             // waves per block
#define R1 4              // item rounds/wave:  256*4*4*4  = 16384 rows
#define R2 2              // user rounds/wave:  512*4*2*4  = 16384 rows

__global__ void __launch_bounds__(NTHREADS)
mf_item_sum(const int* __restrict__ item_idx,
            const float* __restrict__ item_factors,
            float* __restrict__ s_part, int B) {
    const int lane = threadIdx.x & 63;
    const int wid  = threadIdx.x >> 6;
    const int rg   = lane >> 4;
    const int fs   = lane & 15;
    const int waveBase = (blockIdx.x * WPB + wid) * (R1 * 4);  // 16 rows/wave

    int idx[R1];
    #pragma unroll
    for (int r = 0; r < R1; ++r) {
        const int p = waveBase + r * 4 + rg;
        idx[r] = (p < B) ? item_idx[p] : -1;
    }

    float4 acc = make_float4(0.f, 0.f, 0.f, 0.f);
    #pragma unroll
    for (int r = 0; r < R1; ++r) {
        if (idx[r] >= 0) {
            const float4 v = *(const float4*)(item_factors + (size_t)idx[r] * FDIM + fs * 4);
            acc.x += v.x; acc.y += v.y; acc.z += v.z; acc.w += v.w;
        }
    }

    // Sum across the 4 row-groups (lane bits 4,5).
    #pragma unroll
    for (int m = 16; m <= 32; m <<= 1) {
        acc.x += __shfl_xor(acc.x, m);
        acc.y += __shfl_xor(acc.y, m);
        acc.z += __shfl_xor(acc.z, m);
        acc.w += __shfl_xor(acc.w, m);
    }

    // Block reduce across 4 waves, plain-store this block's copy.
    __shared__ float4 red[WPB][16];
    if (lane < 16) red[wid][fs] = acc;
    __syncthreads();
    if (threadIdx.x < 16) {
        const float4 a = red[0][threadIdx.x], b = red[1][threadIdx.x],
                     c = red[2][threadIdx.x], d = red[3][threadIdx.x];
        float4 t;
        t.x = a.x + b.x + c.x + d.x;
        t.y = a.y + b.y + c.y + d.y;
        t.z = a.z + b.z + c.z + d.z;
        t.w = a.w + b.w + c.w + d.w;
        *(float4*)(s_part + blockIdx.x * FDIM + threadIdx.x * 4) = t;
    }
}

__global__ void __launch_bounds__(NTHREADS)
mf_user_dot(const int* __restrict__ user_idx,
            const float* __restrict__ user_factors,
            const float* __restrict__ s_part,
            float* __restrict__ out, int B) {
    const int lane = threadIdx.x & 63;
    const int wid  = threadIdx.x >> 6;
    const int rg   = lane >> 4;
    const int fs   = lane & 15;

    // ---- issue user-row gathers FIRST (independent of s) ----
    const int waveBase = (blockIdx.x * WPB + wid) * (R2 * 4);
    int p[R2], u[R2];
    float4 uv[R2];
    #pragma unroll
    for (int r = 0; r < R2; ++r) {
        p[r] = waveBase + r * 4 + rg;
        u[r] = (p[r] < B) ? user_idx[p[r]] : -1;
    }
    #pragma unroll
    for (int r = 0; r < R2; ++r)
        uv[r] = (u[r] >= 0)
            ? *(const float4*)(user_factors + (size_t)u[r] * FDIM + fs * 4)
            : make_float4(0.f, 0.f, 0.f, 0.f);

    // ---- reduce the 256 s-copies (overlaps with in-flight gathers) ----
    // s_part viewed as [256 copies][16 float4 slices].
    const float4* s_part4 = (const float4*)s_part;
    __shared__ float4 sred[16][16];   // [copy-group][slice]
    __shared__ float4 s_lds4[16];
    {
        const int cg  = threadIdx.x >> 4;    // copy group 0..15
        const int sl  = threadIdx.x & 15;    // float4 slice
        float4 a = make_float4(0.f, 0.f, 0.f, 0.f);
        #pragma unroll
        for (int j = 0; j < 16; ++j) {
            const float4 v = s_part4[(cg * 16 + j) * 16 + sl];
            a.x += v.x; a.y += v.y; a.z += v.z; a.w += v.w;
        }
        sred[cg][sl] = a;
    }
    __syncthreads();
    if (threadIdx.x < 16) {
        float4 a = make_float4(0.f, 0.f, 0.f, 0.f);
        #pragma unroll
        for (int j = 0; j < 16; ++j) {
            const float4 v = sred[j][threadIdx.x];
            a.x += v.x; a.y += v.y; a.z += v.z; a.w += v.w;
        }
        s_lds4[threadIdx.x] = a;
    }
    __syncthreads();
    const float4 s4 = s_lds4[fs];

    // ---- dots: 16-lane group shuffle reduce, slice-0 lane writes ----
    #pragma unroll
    for (int r = 0; r < R2; ++r) {
        float v = uv[r].x * s4.x + uv[r].y * s4.y + uv[r].z * s4.z + uv[r].w * s4.w;
        v += __shfl_xor(v, 1);
        v += __shfl_xor(v, 2);
        v += __shfl_xor(v, 4);
        v += __shfl_xor(v, 8);
        if (fs == 0 && p[r] < B) out[p[r]] = v;
    }
}

extern "C" void kernel_launch(void* const* d_in, const int* in_sizes, int n_in,
                              void* d_out, int out_size, void* d_ws, size_t ws_size,
                              hipStream_t stream) {
    const int*   user_idx     = (const int*)d_in[0];
    const int*   item_idx     = (const int*)d_in[1];
    const float* user_factors = (const float*)d_in[2];
    const float* item_factors = (const float*)d_in[3];
    float*       out          = (float*)d_out;
    float*       s_part       = (float*)d_ws;   // NB1 * FDIM floats = 64 KB
    const int B = in_sizes[0];

    mf_item_sum<<<NB1, NTHREADS, 0, stream>>>(item_idx, item_factors, s_part, B);
    mf_user_dot<<<NB2, NTHREADS, 0, stream>>>(user_idx, user_factors, s_part, out, B);
}

// Round 8
// 13.391 us; speedup vs baseline: 1.0077x; 1.0077x over previous
//
#include <hip/hip_runtime.h>
#include <hip/hip_bf16.h>

// out[b] = dot(user_factors[user_indices[b]], s)
// s[f]   = sum_c item_factors[item_indices[c], f],  F = 64
//
// 2 graph nodes:
//   node 1 mf_gather_sum (256 blocks): gathers item rows (-> s_part[256][64])
//          AND user rows (-> u_g[16384][64] contiguous in ws). Both gather
//          bursts overlap; u_g stores complete at L2 (no in-kernel wait).
//   node 2 mf_dot_pre (256 blocks): streaming coalesced u_g reads (block b
//          reads what block b of node 1 wrote -> same bid%8 XCD -> L2 hits),
//          s_part reduce overlapped, dot, store.
// Lane decomposition: rg = lane>>4 (row 0..3), fs = lane&15 (float4 slice)
// -> one dwordx4 wave-instruction covers 4 full 256 B rows.

#define FDIM 64
#define NB1 256
#define NB2 256
#define NTHREADS 256
#define WPB 4
#define R1 4              // rounds/wave: 256 blk * 4 waves * 4 rnds * 4 rows = 16384
#define R2 4
#define S_PART_BYTES (NB1 * FDIM * 4)   // 64 KB

template <bool PREGATHER>
__global__ void __launch_bounds__(NTHREADS)
mf_gather_sum(const int* __restrict__ item_idx, const int* __restrict__ user_idx,
              const float* __restrict__ item_factors, const float* __restrict__ user_factors,
              float* __restrict__ s_part, float* __restrict__ u_g, int B) {
    const int lane = threadIdx.x & 63;
    const int wid  = threadIdx.x >> 6;
    const int rg   = lane >> 4;
    const int fs   = lane & 15;
    const int waveBase = (blockIdx.x * WPB + wid) * 16;   // 16 rows per wave

    int ip[R1], up[R1];
    #pragma unroll
    for (int r = 0; r < R1; ++r) {
        const int p = waveBase + r * 4 + rg;
        ip[r] = (p < B) ? item_idx[p] : -1;
        up[r] = (PREGATHER && p < B) ? user_idx[p] : -1;
    }

    float4 acc = make_float4(0.f, 0.f, 0.f, 0.f);
    #pragma unroll
    for (int r = 0; r < R1; ++r) {
        const int p = waveBase + r * 4 + rg;
        if (ip[r] >= 0) {
            const float4 v = *(const float4*)(item_factors + (size_t)ip[r] * FDIM + fs * 4);
            acc.x += v.x; acc.y += v.y; acc.z += v.z; acc.w += v.w;
        }
        if (PREGATHER && up[r] >= 0) {
            const float4 uvv = *(const float4*)(user_factors + (size_t)up[r] * FDIM + fs * 4);
            *(float4*)(u_g + (size_t)p * FDIM + fs * 4) = uvv;
        }
    }

    #pragma unroll
    for (int m = 16; m <= 32; m <<= 1) {
        acc.x += __shfl_xor(acc.x, m);
        acc.y += __shfl_xor(acc.y, m);
        acc.z += __shfl_xor(acc.z, m);
        acc.w += __shfl_xor(acc.w, m);
    }

    __shared__ float4 red[WPB][16];
    if (lane < 16) red[wid][fs] = acc;
    __syncthreads();
    if (threadIdx.x < 16) {
        const float4 a = red[0][threadIdx.x], b = red[1][threadIdx.x],
                     c = red[2][threadIdx.x], d = red[3][threadIdx.x];
        float4 t;
        t.x = a.x + b.x + c.x + d.x;
        t.y = a.y + b.y + c.y + d.y;
        t.z = a.z + b.z + c.z + d.z;
        t.w = a.w + b.w + c.w + d.w;
        *(float4*)(s_part + blockIdx.x * FDIM + threadIdx.x * 4) = t;
    }
}

// Shared s-reduce: 256 copies -> s4 slice for this lane's fs.
__device__ __forceinline__ float4 reduce_s(const float* s_part, int fs) {
    const float4* s_part4 = (const float4*)s_part;
    __shared__ float4 sred[16][16];
    __shared__ float4 s_lds4[16];
    {
        const int cg = threadIdx.x >> 4;
        const int sl = threadIdx.x & 15;
        float4 a = make_float4(0.f, 0.f, 0.f, 0.f);
        #pragma unroll
        for (int j = 0; j < 16; ++j) {
            const float4 v = s_part4[(cg * 16 + j) * 16 + sl];
            a.x += v.x; a.y += v.y; a.z += v.z; a.w += v.w;
        }
        sred[cg][sl] = a;
    }
    __syncthreads();
    if (threadIdx.x < 16) {
        float4 a = make_float4(0.f, 0.f, 0.f, 0.f);
        #pragma unroll
        for (int j = 0; j < 16; ++j) {
            const float4 v = sred[j][threadIdx.x];
            a.x += v.x; a.y += v.y; a.z += v.z; a.w += v.w;
        }
        s_lds4[threadIdx.x] = a;
    }
    __syncthreads();
    return s_lds4[fs];
}

__global__ void __launch_bounds__(NTHREADS)
mf_dot_pre(const float* __restrict__ u_g, const float* __restrict__ s_part,
           float* __restrict__ out, int B) {
    const int lane = threadIdx.x & 63;
    const int wid  = threadIdx.x >> 6;
    const int rg   = lane >> 4;
    const int fs   = lane & 15;
    const int waveBase = (blockIdx.x * WPB + wid) * 16;

    float4 uv[R2];
    #pragma unroll
    for (int r = 0; r < R2; ++r) {
        const int p = waveBase + r * 4 + rg;
        uv[r] = (p < B)
            ? *(const float4*)(u_g + (size_t)p * FDIM + fs * 4)
            : make_float4(0.f, 0.f, 0.f, 0.f);
    }

    const float4 s4 = reduce_s(s_part, fs);

    #pragma unroll
    for (int r = 0; r < R2; ++r) {
        const int p = waveBase + r * 4 + rg;
        float v = uv[r].x * s4.x + uv[r].y * s4.y + uv[r].z * s4.z + uv[r].w * s4.w;
        v += __shfl_xor(v, 1);
        v += __shfl_xor(v, 2);
        v += __shfl_xor(v, 4);
        v += __shfl_xor(v, 8);
        if (fs == 0 && p < B) out[p] = v;
    }
}

__global__ void __launch_bounds__(NTHREADS)
mf_user_dot(const int* __restrict__ user_idx,
            const float* __restrict__ user_factors,
            const float* __restrict__ s_part,
            float* __restrict__ out, int B) {
    const int lane = threadIdx.x & 63;
    const int wid  = threadIdx.x >> 6;
    const int rg   = lane >> 4;
    const int fs   = lane & 15;
    const int waveBase = (blockIdx.x * WPB + wid) * 16;

    int p[R2], u[R2];
    float4 uv[R2];
    #pragma unroll
    for (int r = 0; r < R2; ++r) {
        p[r] = waveBase + r * 4 + rg;
        u[r] = (p[r] < B) ? user_idx[p[r]] : -1;
    }
    #pragma unroll
    for (int r = 0; r < R2; ++r)
        uv[r] = (u[r] >= 0)
            ? *(const float4*)(user_factors + (size_t)u[r] * FDIM + fs * 4)
            : make_float4(0.f, 0.f, 0.f, 0.f);

    const float4 s4 = reduce_s(s_part, fs);

    #pragma unroll
    for (int r = 0; r < R2; ++r) {
        float v = uv[r].x * s4.x + uv[r].y * s4.y + uv[r].z * s4.z + uv[r].w * s4.w;
        v += __shfl_xor(v, 1);
        v += __shfl_xor(v, 2);
        v += __shfl_xor(v, 4);
        v += __shfl_xor(v, 8);
        if (fs == 0 && p[r] < B) out[p[r]] = v;
    }
}

extern "C" void kernel_launch(void* const* d_in, const int* in_sizes, int n_in,
                              void* d_out, int out_size, void* d_ws, size_t ws_size,
                              hipStream_t stream) {
    const int*   user_idx     = (const int*)d_in[0];
    const int*   item_idx     = (const int*)d_in[1];
    const float* user_factors = (const float*)d_in[2];
    const float* item_factors = (const float*)d_in[3];
    float*       out          = (float*)d_out;
    float*       s_part       = (float*)d_ws;
    const int B = in_sizes[0];

    const size_t need = (size_t)S_PART_BYTES + (size_t)B * FDIM * 4;
    if (ws_size >= need) {
        float* u_g = (float*)((char*)d_ws + S_PART_BYTES);
        mf_gather_sum<true><<<NB1, NTHREADS, 0, stream>>>(
            item_idx, user_idx, item_factors, user_factors, s_part, u_g, B);
        mf_dot_pre<<<NB2, NTHREADS, 0, stream>>>(u_g, s_part, out, B);
    } else {
        mf_gather_sum<false><<<NB1, NTHREADS, 0, stream>>>(
            item_idx, user_idx, item_factors, user_factors, s_part, nullptr, B);
        mf_user_dot<<<512, NTHREADS, 0, stream>>>(user_idx, user_factors, s_part, out, B);
    }
}